// Round 1
// 509.993 us; speedup vs baseline: 1.0024x; 1.0024x over previous
//
#include <hip/hip_runtime.h>

// SphericalSmearing: real spherical harmonics, MAX_N=16, 500k points.
// out shape (N, 256) fp32 row-major:
//   cols [0,16)    : harm_re for m==0, n=0..15
//   cols [16,136)  : harm_re for m>=1, ordered (n asc, m=1..n), idx = n(n-1)/2 + (m-1)
//   cols [136,256) : harm_im, same ordering, = re col + 120
//
// v2 strategy (occupancy + no-barrier):
//  - block = 64 threads = ONE wave, 64 points/block.
//  - FOUR column-quarter passes (64 cols each). LDS tile = 64 rows x 65 floats
//    = 16.6 KB -> 9 blocks/CU (vs 4 with half-passes) => 2.25 waves/SIMD.
//  - NO __syncthreads(): single-wave block needs only lgkmcnt(0) + compiler
//    memory fence for LDS producer->consumer ordering. No s_barrier means no
//    forced s_waitcnt vmcnt(0) -> global stores from all passes stay in flight.
//  - LDS layout: NATURAL column order, row stride 65 (odd):
//      * staging write (all lanes, same col c): bank = (65t + c)%32 = (t+c)%32
//        -> 2 lanes/bank, free.
//      * flush read: 4 consecutive dwords at row*65 + 4*c4; per instruction
//        bank = (row + 4*c4 + j)%32 with row = 4*it + (t>>4), c4 = t&15:
//        hi + 4*c4 is a bijection on [0,64) -> exactly 2 lanes/bank, free.
//        Consecutive dwords also merge into ds_read2_b32.
//  - Flush global stores: lanes 0-15 write one 256B contiguous chunk per row,
//    4 rows per wave instruction -> fully coalesced float4 stores.

#define NMAX   16
#define BLOCK  64
#define QCOLS  64
#define STRIDE 65   // floats per LDS row (64 data + 1 pad, odd => conflict-free)

// ---- compile-time coefficient table ----
constexpr double cfact(int k) { double r = 1.0; for (int i = 2; i <= k; ++i) r *= (double)i; return r; }
constexpr double csqrt_(double x) {
    double g = x > 1.0 ? x : 1.0;
    for (int i = 0; i < 120; ++i) g = 0.5 * (g + x / g);
    return g;
}
constexpr double PI_ = 3.14159265358979323846;

struct CoefTab { float c[NMAX][NMAX]; };
constexpr CoefTab make_coef() {
    CoefTab t{};
    for (int n = 0; n < NMAX; ++n)
        for (int m = 0; m <= n; ++m)
            t.c[n][m] = (float)csqrt_(((2.0 * n + 1.0) / (4.0 * PI_)) * cfact(n - m) / cfact(n + m));
    return t;
}
constexpr CoefTab COEF = make_coef();

// Wave-local LDS fence: block == 1 wave, so lgkmcnt(0) makes all lanes' LDS
// writes visible to subsequent reads (and completed reads safe against
// overwrite). "memory" clobber pins compiler ordering of LDS ops around it.
__device__ __forceinline__ void wave_lds_fence() {
    asm volatile("s_waitcnt lgkmcnt(0)" ::: "memory");
}

// ---- staging helpers (fold to single ds_write w/ imm offset, or nothing) ----
template <int PASS>
__device__ __forceinline__ void stage(float* rowPtr, int col, float v) {
    constexpr int lo = PASS * QCOLS;
    if (col >= lo && col < lo + QCOLS) {
        rowPtr[col - lo] = v;          // natural order; compile-time offset
    }
}

template <int PASS>
__device__ __forceinline__ void emit(float* rowPtr, int n, int m, float p, float cm, float sm) {
    float v = COEF.c[n][m] * p;
    if (m == 0) {
        stage<PASS>(rowPtr, n, v);
    } else {
        int col = 16 + (n * (n - 1)) / 2 + (m - 1);
        stage<PASS>(rowPtr, col, v * cm);         // re
        stage<PASS>(rowPtr, col + 120, v * sm);   // im
    }
}

template <int PASS>
__device__ __forceinline__ void compute_stage(float ct, float st, float c1, float s1, float* rowPtr) {
    float pmm = 1.0f;           // P[m][m]
    float cm = 1.0f, sm = 0.0f; // cos(m*phi), sin(m*phi)
#pragma unroll
    for (int m = 0; m < NMAX; ++m) {
        emit<PASS>(rowPtr, m, m, pmm, cm, sm);
        float pn2 = pmm;
        if (m < NMAX - 1) {
            float pn1 = (float)(2 * m + 1) * ct * pmm;
            emit<PASS>(rowPtr, m + 1, m, pn1, cm, sm);
#pragma unroll
            for (int n = m + 2; n < NMAX; ++n) {
                float pn = ((float)(2 * n - 1) * ct * pn1 - (float)(n + m - 1) * pn2)
                           * (1.0f / (float)(n - m));
                emit<PASS>(rowPtr, n, m, pn, cm, sm);
                pn2 = pn1;
                pn1 = pn;
            }
        }
        pmm = -(float)(2 * m + 1) * st * pmm;     // P[m+1][m+1]
        float cn = cm * c1 - sm * s1;             // angle-addition
        sm = sm * c1 + cm * s1;
        cm = cn;
    }
}

// ---- flush one quarter: LDS -> coalesced float4 global stores ----
template <int PASS>
__device__ __forceinline__ void flush(const float* tile, float* out,
                                      long long rowBase, int npts, int t, bool tail) {
    const int hi = t >> 4;        // row-within-group 0..3
    const int c4 = t & 15;        // float4 slot within quarter row
    const float* p0 = tile + hi * STRIDE + 4 * c4;
    float* o0 = out + (rowBase + hi) * 256 + PASS * QCOLS + 4 * c4;
#pragma unroll
    for (int it = 0; it < 16; ++it) {
        if (!tail || (rowBase + it * 4 + hi) < (long long)npts) {
            const float* p = p0 + it * (4 * STRIDE);
            float4 v = make_float4(p[0], p[1], p[2], p[3]);   // dword reads (dword-aligned only)
            *reinterpret_cast<float4*>(o0 + it * 4 * 256) = v;
        }
    }
}

__global__ __launch_bounds__(BLOCK)
void sph_harm_kernel(const float* __restrict__ xyz, float* __restrict__ out, int npts) {
    __shared__ float tile[BLOCK * STRIDE];   // 16,640 B -> 9 blocks/CU
    const int t = threadIdx.x;
    const long long rowBase = (long long)blockIdx.x * BLOCK;
    long long pt = rowBase + t;
    long long cpt = pt < npts ? pt : (long long)npts - 1;
    const bool tail = (rowBase + BLOCK) > (long long)npts;

    float x = xyz[3 * cpt + 0];
    float y = xyz[3 * cpt + 1];
    float z = xyz[3 * cpt + 2];

    float r2 = x * x + y * y + z * z;
    float r  = sqrtf(r2);
    float ct = z / r;
    float st = sqrtf(fmaxf(1.0f - ct * ct, 0.0f));

    float rho2 = x * x + y * y;
    float c1, s1;
    if (rho2 > 0.0f) {
        float rinv = 1.0f / sqrtf(rho2);
        c1 = x * rinv;
        s1 = y * rinv;
    } else {
        c1 = 1.0f;  // theta = atan2(-0,-0)+pi -> 0
        s1 = 0.0f;
    }

    float* rowPtr = tile + t * STRIDE;

    compute_stage<0>(ct, st, c1, s1, rowPtr);
    wave_lds_fence();
    flush<0>(tile, out, rowBase, npts, t, tail);
    wave_lds_fence();                     // flush reads done before overwrite

    compute_stage<1>(ct, st, c1, s1, rowPtr);
    wave_lds_fence();
    flush<1>(tile, out, rowBase, npts, t, tail);
    wave_lds_fence();

    compute_stage<2>(ct, st, c1, s1, rowPtr);
    wave_lds_fence();
    flush<2>(tile, out, rowBase, npts, t, tail);
    wave_lds_fence();

    compute_stage<3>(ct, st, c1, s1, rowPtr);
    wave_lds_fence();
    flush<3>(tile, out, rowBase, npts, t, tail);
    // no drain needed: kernel end waits stores automatically
}

extern "C" void kernel_launch(void* const* d_in, const int* in_sizes, int n_in,
                              void* d_out, int out_size, void* d_ws, size_t ws_size,
                              hipStream_t stream) {
    const float* xyz = (const float*)d_in[0];
    float* out = (float*)d_out;
    int npts = in_sizes[0] / 3;
    int blocks = (npts + BLOCK - 1) / BLOCK;
    hipLaunchKernelGGL(sph_harm_kernel, dim3(blocks), dim3(BLOCK), 0, stream,
                       xyz, out, npts);
}

// Round 2
// 506.614 us; speedup vs baseline: 1.0091x; 1.0067x over previous
//
#include <hip/hip_runtime.h>

// SphericalSmearing: real spherical harmonics, MAX_N=16, 500k points.
// out shape (N, 256) fp32 row-major:
//   cols [0,16)    : harm_re for m==0, n=0..15
//   cols [16,136)  : harm_re for m>=1, ordered (n asc, m=1..n), idx = n(n-1)/2 + (m-1)
//   cols [136,256) : harm_im, same ordering, = re col + 120
//
// v3 strategy (fill-shaped linear writes):
//  Evidence: three structurally different variants all pin at ~180us kernel
//  (~2.8 TB/s write) while the harness fill hits 6.2 TB/s on the same buffer.
//  Shared trait of the stuck variants: partial-row strided stores (256B used
//  per 1024B row per pass). This version makes the store stream DENSE+LINEAR:
//
//  - block = 64 threads = ONE wave, 16 points/block.
//  - 4-lane-redundant compute: every lane runs the full recurrence for point
//    p = t>>2 (VALU has >5x headroom); lane stages only its owned quarter
//    q_own = t&3 of the 256 columns into LDS. Non-owned emit sites write to a
//    per-lane dump slot. Quarter selection is via FOUR named base pointers
//    chosen per-site at COMPILE TIME (col>>6 folds) -> one plain ds_write per
//    site, zero divergence, no runtime-indexed arrays (no scratch).
//  - LDS tile 16 rows x 257 dwords + 128-dword dump = 16,960 B -> 9 blocks/CU
//    (2.25 waves/SIMD), barrier-free (single wave, lgkmcnt fence only).
//  - Flush: block's output region out[row0*256 .. (row0+16)*256) is 16 KB
//    CONTIGUOUS. 16 wave-stores of 1 KB each, consecutive addresses ->
//    byte-identical pattern to the 6.2 TB/s fill. LDS flush reads are
//    row-linear (conflict-free).

#define NMAX   16
#define BLOCK  64
#define PPB    16                 // points per block
#define STRIDE 257                // dwords per LDS row (odd -> conflict-free staging)
#define DUMPO  (PPB * STRIDE)     // dump region base (dwords) = 4112
#define TILEF  (DUMPO + 128)      // 4240 dwords = 16,960 B

// ---- compile-time coefficient table ----
constexpr double cfact(int k) { double r = 1.0; for (int i = 2; i <= k; ++i) r *= (double)i; return r; }
constexpr double csqrt_(double x) {
    double g = x > 1.0 ? x : 1.0;
    for (int i = 0; i < 120; ++i) g = 0.5 * (g + x / g);
    return g;
}
constexpr double PI_ = 3.14159265358979323846;

struct CoefTab { float c[NMAX][NMAX]; };
constexpr CoefTab make_coef() {
    CoefTab t{};
    for (int n = 0; n < NMAX; ++n)
        for (int m = 0; m <= n; ++m)
            t.c[n][m] = (float)csqrt_(((2.0 * n + 1.0) / (4.0 * PI_)) * cfact(n - m) / cfact(n + m));
    return t;
}
constexpr CoefTab COEF = make_coef();

// Wave-local LDS fence: block == 1 wave, so lgkmcnt(0) makes all lanes' LDS
// writes visible to subsequent reads. "memory" clobber pins compiler ordering.
__device__ __forceinline__ void wave_lds_fence() {
    asm volatile("s_waitcnt lgkmcnt(0)" ::: "memory");
}

// ---- staging: compile-time quarter -> named base pointer, single ds_write ----
__device__ __forceinline__ void stageq(float* b0, float* b1, float* b2, float* b3,
                                       int col, float v) {
    const int q   = col >> 6;     // constant after inline+unroll
    const int off = col & 63;
    float* b = (q == 0) ? b0 : (q == 1) ? b1 : (q == 2) ? b2 : b3;
    b[off] = v;                   // imm-offset ds_write_b32
}

__device__ __forceinline__ void emit(float* b0, float* b1, float* b2, float* b3,
                                     int n, int m, float p, float cm, float sm) {
    float v = COEF.c[n][m] * p;
    if (m == 0) {
        stageq(b0, b1, b2, b3, n, v);
    } else {
        int col = 16 + (n * (n - 1)) / 2 + (m - 1);
        stageq(b0, b1, b2, b3, col,       v * cm);   // re
        stageq(b0, b1, b2, b3, col + 120, v * sm);   // im
    }
}

__device__ __forceinline__ void compute_stage(float ct, float st, float c1, float s1,
                                              float* b0, float* b1, float* b2, float* b3) {
    float pmm = 1.0f;           // P[m][m]
    float cm = 1.0f, sm = 0.0f; // cos(m*phi), sin(m*phi)
#pragma unroll
    for (int m = 0; m < NMAX; ++m) {
        emit(b0, b1, b2, b3, m, m, pmm, cm, sm);
        float pn2 = pmm;
        if (m < NMAX - 1) {
            float pn1 = (float)(2 * m + 1) * ct * pmm;
            emit(b0, b1, b2, b3, m + 1, m, pn1, cm, sm);
#pragma unroll
            for (int n = m + 2; n < NMAX; ++n) {
                float pn = ((float)(2 * n - 1) * ct * pn1 - (float)(n + m - 1) * pn2)
                           * (1.0f / (float)(n - m));
                emit(b0, b1, b2, b3, n, m, pn, cm, sm);
                pn2 = pn1;
                pn1 = pn;
            }
        }
        pmm = -(float)(2 * m + 1) * st * pmm;     // P[m+1][m+1]
        float cn = cm * c1 - sm * s1;             // angle-addition
        sm = sm * c1 + cm * s1;
        cm = cn;
    }
}

__global__ __launch_bounds__(BLOCK)
void sph_harm_kernel(const float* __restrict__ xyz, float* __restrict__ out, int npts) {
    __shared__ float tile[TILEF];
    const int t   = threadIdx.x;
    const int p   = t >> 2;       // point-within-block 0..15
    const int sub = t & 3;        // owned column-quarter
    const long long row0 = (long long)blockIdx.x * PPB;
    long long pt  = row0 + p;
    long long cpt = pt < npts ? pt : (long long)npts - 1;

    float x = xyz[3 * cpt + 0];
    float y = xyz[3 * cpt + 1];
    float z = xyz[3 * cpt + 2];

    float r2 = x * x + y * y + z * z;
    float r  = sqrtf(r2);
    float ct = z / r;
    float st = sqrtf(fmaxf(1.0f - ct * ct, 0.0f));

    float rho2 = x * x + y * y;
    float c1, s1;
    if (rho2 > 0.0f) {
        float rinv = 1.0f / sqrtf(rho2);
        c1 = x * rinv;
        s1 = y * rinv;
    } else {
        c1 = 1.0f;  // theta = atan2(-0,-0)+pi -> 0
        s1 = 0.0f;
    }

    // Quarter-ownership base pointers: owned quarter -> real row slot,
    // the other three -> per-lane dump slot (conflict-light, discarded).
    float* rowQ = tile + p * STRIDE + sub * 64;
    float* dump = tile + DUMPO + t;
    float* b0 = (sub == 0) ? rowQ : dump;
    float* b1 = (sub == 1) ? rowQ : dump;
    float* b2 = (sub == 2) ? rowQ : dump;
    float* b3 = (sub == 3) ? rowQ : dump;

    compute_stage(ct, st, c1, s1, b0, b1, b2, b3);

    wave_lds_fence();

    // Flush: 16 KB contiguous, 1 KB per wave-store instruction, linear.
    const bool tail = (row0 + PPB) > (long long)npts;
    float* o0 = out + row0 * 256 + 4 * t;
#pragma unroll
    for (int it = 0; it < PPB; ++it) {
        if (!tail || (row0 + it) < (long long)npts) {
            const float* q = tile + it * STRIDE + 4 * t;   // row-linear, conflict-free
            float4 v = make_float4(q[0], q[1], q[2], q[3]); // dword reads (4B-aligned)
            *reinterpret_cast<float4*>(o0 + it * 256) = v;  // 16B-aligned global store
        }
    }
}

extern "C" void kernel_launch(void* const* d_in, const int* in_sizes, int n_in,
                              void* d_out, int out_size, void* d_ws, size_t ws_size,
                              hipStream_t stream) {
    const float* xyz = (const float*)d_in[0];
    float* out = (float*)d_out;
    int npts = in_sizes[0] / 3;
    int blocks = (npts + PPB - 1) / PPB;
    hipLaunchKernelGGL(sph_harm_kernel, dim3(blocks), dim3(BLOCK), 0, stream,
                       xyz, out, npts);
}

// Round 4
// 506.115 us; speedup vs baseline: 1.0101x; 1.0010x over previous
//
#include <hip/hip_runtime.h>

// SphericalSmearing: real spherical harmonics, MAX_N=16, 500k points.
// out shape (N, 256) fp32 row-major:
//   cols [0,16)    : harm_re for m==0, n=0..15
//   cols [16,136)  : harm_re for m>=1, ordered (n asc, m=1..n), idx = n(n-1)/2 + (m-1)
//   cols [136,256) : harm_im, same ordering, = re col + 120
//
// v4b = v3 + NONTEMPORAL STORES (single-variable change; v4 fixed).
//  v4 failed to compile: __builtin_nontemporal_store rejects HIP_vector_type
//  float4. Fix: native ext_vector_type(4) float -> same global_store_dwordx4
//  with nt flag.
//  Theory under test (from round-2 post-mortem): all variants pin at ~180us
//  kernel (~2.8 TB/s) vs the 6.2 TB/s harness fill whose FETCH_SIZE ~ 0.
//  If plain stores write-allocate (fetch victim lines from HBM before full
//  overwrite), HBM traffic doubles to ~1 GB -> exactly ~180us. nt stores take
//  the no-allocate/streaming path. Predict kernel ~180 -> ~95-105us if theory
//  holds; unchanged -> falsified, declare roofline.
//
//  Structure (unchanged from v3):
//  - block = 64 threads = ONE wave, 16 points/block.
//  - 4-lane-redundant compute: every lane runs the full recurrence for point
//    p = t>>2; lane stages only its owned quarter q_own = t&3 into LDS;
//    non-owned emit sites go to a per-lane dump slot (compile-time base
//    pointer select, zero divergence, no scratch).
//  - LDS 16x257 + 128 dump = 16,960 B -> 9 blocks/CU, barrier-free.
//  - Flush: 16 KB contiguous block output, 1 KB per wave-store, linear.

#define NMAX   16
#define BLOCK  64
#define PPB    16                 // points per block
#define STRIDE 257                // dwords per LDS row (odd -> conflict-free staging)
#define DUMPO  (PPB * STRIDE)     // dump region base (dwords) = 4112
#define TILEF  (DUMPO + 128)      // 4240 dwords = 16,960 B

typedef float vfloat4 __attribute__((ext_vector_type(4)));  // native vec for nt builtin

// ---- compile-time coefficient table ----
constexpr double cfact(int k) { double r = 1.0; for (int i = 2; i <= k; ++i) r *= (double)i; return r; }
constexpr double csqrt_(double x) {
    double g = x > 1.0 ? x : 1.0;
    for (int i = 0; i < 120; ++i) g = 0.5 * (g + x / g);
    return g;
}
constexpr double PI_ = 3.14159265358979323846;

struct CoefTab { float c[NMAX][NMAX]; };
constexpr CoefTab make_coef() {
    CoefTab t{};
    for (int n = 0; n < NMAX; ++n)
        for (int m = 0; m <= n; ++m)
            t.c[n][m] = (float)csqrt_(((2.0 * n + 1.0) / (4.0 * PI_)) * cfact(n - m) / cfact(n + m));
    return t;
}
constexpr CoefTab COEF = make_coef();

// Wave-local LDS fence: block == 1 wave, so lgkmcnt(0) makes all lanes' LDS
// writes visible to subsequent reads. "memory" clobber pins compiler ordering.
__device__ __forceinline__ void wave_lds_fence() {
    asm volatile("s_waitcnt lgkmcnt(0)" ::: "memory");
}

// ---- staging: compile-time quarter -> named base pointer, single ds_write ----
__device__ __forceinline__ void stageq(float* b0, float* b1, float* b2, float* b3,
                                       int col, float v) {
    const int q   = col >> 6;     // constant after inline+unroll
    const int off = col & 63;
    float* b = (q == 0) ? b0 : (q == 1) ? b1 : (q == 2) ? b2 : b3;
    b[off] = v;                   // imm-offset ds_write_b32
}

__device__ __forceinline__ void emit(float* b0, float* b1, float* b2, float* b3,
                                     int n, int m, float p, float cm, float sm) {
    float v = COEF.c[n][m] * p;
    if (m == 0) {
        stageq(b0, b1, b2, b3, n, v);
    } else {
        int col = 16 + (n * (n - 1)) / 2 + (m - 1);
        stageq(b0, b1, b2, b3, col,       v * cm);   // re
        stageq(b0, b1, b2, b3, col + 120, v * sm);   // im
    }
}

__device__ __forceinline__ void compute_stage(float ct, float st, float c1, float s1,
                                              float* b0, float* b1, float* b2, float* b3) {
    float pmm = 1.0f;           // P[m][m]
    float cm = 1.0f, sm = 0.0f; // cos(m*phi), sin(m*phi)
#pragma unroll
    for (int m = 0; m < NMAX; ++m) {
        emit(b0, b1, b2, b3, m, m, pmm, cm, sm);
        float pn2 = pmm;
        if (m < NMAX - 1) {
            float pn1 = (float)(2 * m + 1) * ct * pmm;
            emit(b0, b1, b2, b3, m + 1, m, pn1, cm, sm);
#pragma unroll
            for (int n = m + 2; n < NMAX; ++n) {
                float pn = ((float)(2 * n - 1) * ct * pn1 - (float)(n + m - 1) * pn2)
                           * (1.0f / (float)(n - m));
                emit(b0, b1, b2, b3, n, m, pn, cm, sm);
                pn2 = pn1;
                pn1 = pn;
            }
        }
        pmm = -(float)(2 * m + 1) * st * pmm;     // P[m+1][m+1]
        float cn = cm * c1 - sm * s1;             // angle-addition
        sm = sm * c1 + cm * s1;
        cm = cn;
    }
}

__global__ __launch_bounds__(BLOCK)
void sph_harm_kernel(const float* __restrict__ xyz, float* __restrict__ out, int npts) {
    __shared__ float tile[TILEF];
    const int t   = threadIdx.x;
    const int p   = t >> 2;       // point-within-block 0..15
    const int sub = t & 3;        // owned column-quarter
    const long long row0 = (long long)blockIdx.x * PPB;
    long long pt  = row0 + p;
    long long cpt = pt < npts ? pt : (long long)npts - 1;

    float x = xyz[3 * cpt + 0];
    float y = xyz[3 * cpt + 1];
    float z = xyz[3 * cpt + 2];

    float r2 = x * x + y * y + z * z;
    float r  = sqrtf(r2);
    float ct = z / r;
    float st = sqrtf(fmaxf(1.0f - ct * ct, 0.0f));

    float rho2 = x * x + y * y;
    float c1, s1;
    if (rho2 > 0.0f) {
        float rinv = 1.0f / sqrtf(rho2);
        c1 = x * rinv;
        s1 = y * rinv;
    } else {
        c1 = 1.0f;  // theta = atan2(-0,-0)+pi -> 0
        s1 = 0.0f;
    }

    // Quarter-ownership base pointers: owned quarter -> real row slot,
    // the other three -> per-lane dump slot (conflict-light, discarded).
    float* rowQ = tile + p * STRIDE + sub * 64;
    float* dump = tile + DUMPO + t;
    float* b0 = (sub == 0) ? rowQ : dump;
    float* b1 = (sub == 1) ? rowQ : dump;
    float* b2 = (sub == 2) ? rowQ : dump;
    float* b3 = (sub == 3) ? rowQ : dump;

    compute_stage(ct, st, c1, s1, b0, b1, b2, b3);

    wave_lds_fence();

    // Flush: 16 KB contiguous, 1 KB per wave-store instruction, linear.
    // NONTEMPORAL: no-allocate / streaming path (the v4 experiment).
    const bool tail = (row0 + PPB) > (long long)npts;
    float* o0 = out + row0 * 256 + 4 * t;
#pragma unroll
    for (int it = 0; it < PPB; ++it) {
        if (!tail || (row0 + it) < (long long)npts) {
            const float* q = tile + it * STRIDE + 4 * t;   // row-linear, conflict-free
            vfloat4 v = { q[0], q[1], q[2], q[3] };         // dword reads (4B-aligned)
            __builtin_nontemporal_store(v,
                reinterpret_cast<vfloat4*>(o0 + it * 256)); // global_store_dwordx4 nt
        }
    }
}

extern "C" void kernel_launch(void* const* d_in, const int* in_sizes, int n_in,
                              void* d_out, int out_size, void* d_ws, size_t ws_size,
                              hipStream_t stream) {
    const float* xyz = (const float*)d_in[0];
    float* out = (float*)d_out;
    int npts = in_sizes[0] / 3;
    int blocks = (npts + PPB - 1) / PPB;
    hipLaunchKernelGGL(sph_harm_kernel, dim3(blocks), dim3(BLOCK), 0, stream,
                       xyz, out, npts);
}